// Round 1
// baseline (769.117 us; speedup 1.0000x reference)
//
#include <hip/hip_runtime.h>
#include <stdint.h>
#include <math.h>

#define NTOK 2048
#define HDIM 2048
#define FDIM 1024
#define FSD  2048
#define NEXP 32
#define TOPK 4
#define NGRP 4
#define CAP  512

typedef _Float16 f16;
typedef _Float16 half8 __attribute__((ext_vector_type(8)));
typedef float f32x4 __attribute__((ext_vector_type(4)));

// ---------------- convert x (fp32) -> xb (fp16) ----------------
__global__ __launch_bounds__(256) void convert_kernel(const float* __restrict__ x,
                                                      f16* __restrict__ xb, int n8) {
  int i = blockIdx.x * 256 + threadIdx.x;
  if (i >= n8) return;
  const float4* p = (const float4*)(x + (size_t)i * 8);
  float4 a = p[0], b = p[1];
  half8 v;
  v[0] = (f16)a.x; v[1] = (f16)a.y; v[2] = (f16)a.z; v[3] = (f16)a.w;
  v[4] = (f16)b.x; v[5] = (f16)b.y; v[6] = (f16)b.z; v[7] = (f16)b.w;
  *(half8*)(xb + (size_t)i * 8) = v;
}

// ---------------- gate: logits -> sigmoid -> group top2 -> top4 ----------------
__global__ __launch_bounds__(256) void gate_kernel(const float* __restrict__ x,
                                                   const float* __restrict__ gw,
                                                   const float* __restrict__ gb,
                                                   int* __restrict__ tidx,
                                                   float* __restrict__ tw) {
  int t = blockIdx.x;
  int tid = threadIdx.x;
  int e = tid >> 3, p = tid & 7;
  const float* xr = x + (size_t)t * HDIM;
  const float* wr = gw + (size_t)e * HDIM;
  float s = 0.f;
  for (int i = p; i < HDIM; i += 8) s += xr[i] * wr[i];
  s += __shfl_down(s, 4, 8);
  s += __shfl_down(s, 2, 8);
  s += __shfl_down(s, 1, 8);
  __shared__ float lg[NEXP];
  if (p == 0) lg[e] = s;
  __syncthreads();
  if (tid == 0) {
    float sc[NEXP], scb[NEXP];
    for (int i = 0; i < NEXP; i++) {
      sc[i] = 1.f / (1.f + expf(-lg[i]));
      scb[i] = sc[i] + gb[i];
    }
    // group scores = sum of top-2 within each group of 8
    float gs[NGRP];
    for (int g = 0; g < NGRP; g++) {
      float m1 = -1e30f, m2 = -1e30f;
      for (int j = 0; j < 8; j++) {
        float v = scb[g * 8 + j];
        if (v > m1) { m2 = m1; m1 = v; }
        else if (v > m2) m2 = v;
      }
      gs[g] = m1 + m2;
    }
    // top-2 groups (ties -> lowest index, matching lax.top_k)
    int g1 = 0; float bv = gs[0];
    for (int g = 1; g < NGRP; g++) if (gs[g] > bv) { bv = gs[g]; g1 = g; }
    int g2 = -1; bv = -1e30f;
    for (int g = 0; g < NGRP; g++) if (g != g1 && gs[g] > bv) { bv = gs[g]; g2 = g; }
    // candidates: masked-out groups contribute 0.0 (reference uses where(...,sc,0))
    float cand[NEXP];
    for (int i = 0; i < NEXP; i++) {
      int g = i >> 3;
      cand[i] = (g == g1 || g == g2) ? scb[i] : 0.0f;
    }
    int isel[TOPK]; float wsel[TOPK]; float wsum = 0.f;
    bool used[NEXP] = {};
    for (int k = 0; k < TOPK; k++) {
      int best = 0; float bw = -1e30f;
      for (int i = 0; i < NEXP; i++)
        if (!used[i] && cand[i] > bw) { bw = cand[i]; best = i; }
      used[best] = true;
      isel[k] = best;
      wsel[k] = sc[best];   // weight uses sigmoid score WITHOUT bias
      wsum += wsel[k];
    }
    float inv = 2.0f / (wsum + 1e-20f);   // renorm * routed_scaling_factor
    for (int k = 0; k < TOPK; k++) {
      tidx[t * TOPK + k] = isel[k];
      tw[t * TOPK + k] = wsel[k] * inv;
    }
  }
}

// ---------------- dispatch: ordered compaction per expert (exact drop semantics) ----------------
__global__ __launch_bounds__(256) void dispatch_kernel(const int* __restrict__ tidx,
                                                       const float* __restrict__ tw,
                                                       int* __restrict__ tok,
                                                       float* __restrict__ wt,
                                                       int* __restrict__ cnt) {
  int e = blockIdx.x, tid = threadIdx.x, wv = tid >> 6, lane = tid & 63;
  __shared__ int wsum[4];
  __shared__ int sbase;
  if (tid == 0) sbase = 0;
  __syncthreads();
  for (int c = 0; c < (NTOK * TOPK) / 256; c++) {
    int i = c * 256 + tid;
    int fe = tidx[i];
    bool flag = (fe == e);
    unsigned long long b = __ballot(flag ? 1 : 0);
    int lr = __popcll(b & ((1ull << lane) - 1ull));
    if (lane == 0) wsum[wv] = __popcll(b);
    __syncthreads();
    int off = 0;
    for (int w2 = 0; w2 < wv; w2++) off += wsum[w2];
    int tot = wsum[0] + wsum[1] + wsum[2] + wsum[3];
    int base = sbase;
    if (flag) {
      int pos = base + off + lr;
      if (pos < CAP) {
        tok[e * CAP + pos] = i >> 2;   // token index
        wt[e * CAP + pos] = tw[i];
      }
    }
    __syncthreads();
    if (tid == 0) sbase = base + tot;
  }
  __syncthreads();
  if (tid == 0) cnt[e] = min(sbase, CAP);
}

// ---------------- MFMA GEMM ----------------
// MODE 0: routed up   (dual B w1/w3, A gathered from xb, out = silu(g)*u -> h[e] fp16)
// MODE 1: shared up   (dual B sg/su, A linear xb, out -> hs fp16)
// MODE 2: routed down (single B w2, A = h[e], out: atomicAdd(out[token], w*val))
// MODE 3: shared down (single B sd, A = hs, out: plain fp32 store)
__device__ __forceinline__ int swz(int r) { return (r ^ (r >> 3)) & 7; }

template<int MODE, int BN>
__global__ __launch_bounds__(256) void gemm_kernel(
    const f16* __restrict__ Abase, const float* __restrict__ B0g, const float* __restrict__ B1g,
    void* __restrict__ OutP, const int* __restrict__ tokL, const float* __restrict__ wtL,
    const int* __restrict__ cntP, int M, int K, int N, int ldA) {
  constexpr int BM = 128, BK = 64;
  constexpr bool DUAL = (MODE == 0 || MODE == 1);
  constexpr bool ROUTED = (MODE == 0 || MODE == 2);
  constexpr int NF = BN / 32;     // 16-wide n-frags per wave
  constexpr int WN = BN / 2;      // wave n extent

  int e = blockIdx.z;
  int m0 = blockIdx.x * BM, n0 = blockIdx.y * BN;
  int Mcur = M;
  const f16* A = Abase;
  const float* B0 = B0g;
  const float* B1 = B1g;
  const int* tok = tokL;
  const float* wtl = wtL;
  if (ROUTED) {
    Mcur = cntP[e];
    if (m0 >= Mcur) return;
    B0 += (size_t)e * K * N;
    if (DUAL) B1 += (size_t)e * K * N;
    tok += e * CAP;
    wtl += e * CAP;
    if (MODE == 2) A += (size_t)e * CAP * FDIM;
  }

  __shared__ __align__(16) char smem[(BM * BK + (DUAL ? 2 : 1) * BN * BK) * 2];
  char* As = smem;
  char* Bs0 = smem + BM * BK * 2;
  char* Bs1 = Bs0 + BN * BK * 2;

  int tid = threadIdx.x, lane = tid & 63, wv = tid >> 6;
  int wm = (wv >> 1) * 64, wn = (wv & 1) * WN;

  // A staging row pointers (4 chunks of 16B per thread, fixed rows across K loop)
  const f16* arow[4];
#pragma unroll
  for (int j = 0; j < 4; j++) {
    int cid = j * 256 + tid;
    int r = cid >> 3;
    int gr = m0 + r;
    if (MODE == 0) {
      int rr = gr < Mcur ? gr : (Mcur - 1);
      arow[j] = A + (size_t)tok[rr] * ldA;
    } else {
      arow[j] = A + (size_t)gr * ldA;
    }
  }

  f32x4 acc0[4][NF];
  f32x4 acc1[4][NF];
#pragma unroll
  for (int mf = 0; mf < 4; mf++)
#pragma unroll
    for (int nf = 0; nf < NF; nf++) {
      acc0[mf][nf] = (f32x4){0.f, 0.f, 0.f, 0.f};
      acc1[mf][nf] = (f32x4){0.f, 0.f, 0.f, 0.f};
    }

  int nk = K / BK;
  for (int t = 0; t < nk; t++) {
    int k0 = t * BK;
    __syncthreads();
    // stage A: 128 x 64 f16, swizzled 16B chunks
#pragma unroll
    for (int j = 0; j < 4; j++) {
      int cid = j * 256 + tid;
      int r = cid >> 3, c = cid & 7;
      uint4 v = *(const uint4*)(arow[j] + k0 + c * 8);
      *(uint4*)(As + r * 128 + ((c ^ swz(r)) << 4)) = v;
    }
    // stage B (transpose fp32 [k][n] -> LDS [n][k] fp16, swizzled)
    constexpr int PASS = (BK * BN) / 1024;
#pragma unroll
    for (int p = 0; p < PASS; p++) {
      int eid = p * 1024 + tid * 4;
      int kl = eid / BN, nn = eid % BN;
      const float* src0 = B0 + (size_t)(k0 + kl) * N + n0 + nn;
      float4 v0 = *(const float4*)src0;
      {
        float vv[4] = {v0.x, v0.y, v0.z, v0.w};
#pragma unroll
        for (int q = 0; q < 4; q++) {
          int n = nn + q;
          *(f16*)(Bs0 + n * 128 + (((kl >> 3) ^ swz(n)) << 4) + (kl & 7) * 2) = (f16)vv[q];
        }
      }
      if (DUAL) {
        const float* src1 = B1 + (size_t)(k0 + kl) * N + n0 + nn;
        float4 v1 = *(const float4*)src1;
        float vv[4] = {v1.x, v1.y, v1.z, v1.w};
#pragma unroll
        for (int q = 0; q < 4; q++) {
          int n = nn + q;
          *(f16*)(Bs1 + n * 128 + (((kl >> 3) ^ swz(n)) << 4) + (kl & 7) * 2) = (f16)vv[q];
        }
      }
    }
    __syncthreads();
    // compute: 2 mfma K-steps of 32 per K-tile
#pragma unroll
    for (int kk = 0; kk < 2; kk++) {
      half8 af[4];
#pragma unroll
      for (int mf = 0; mf < 4; mf++) {
        int r = wm + mf * 16 + (lane & 15);
        af[mf] = *(const half8*)(As + r * 128 + ((((kk << 2) + (lane >> 4)) ^ swz(r)) << 4));
      }
      half8 bf0[NF], bf1[NF];
#pragma unroll
      for (int nf = 0; nf < NF; nf++) {
        int n = wn + nf * 16 + (lane & 15);
        int off = n * 128 + ((((kk << 2) + (lane >> 4)) ^ swz(n)) << 4);
        bf0[nf] = *(const half8*)(Bs0 + off);
        if (DUAL) bf1[nf] = *(const half8*)(Bs1 + off);
      }
#pragma unroll
      for (int mf = 0; mf < 4; mf++)
#pragma unroll
        for (int nf = 0; nf < NF; nf++) {
          acc0[mf][nf] = __builtin_amdgcn_mfma_f32_16x16x32_f16(af[mf], bf0[nf], acc0[mf][nf], 0, 0, 0);
          if (DUAL)
            acc1[mf][nf] = __builtin_amdgcn_mfma_f32_16x16x32_f16(af[mf], bf1[nf], acc1[mf][nf], 0, 0, 0);
        }
    }
  }

  // epilogue
  if (MODE == 0 || MODE == 1) {
    f16* Hout = (f16*)OutP;
    if (MODE == 0) Hout += (size_t)e * CAP * FDIM;
#pragma unroll
    for (int mf = 0; mf < 4; mf++) {
      int rb = wm + mf * 16 + ((lane >> 4) << 2);
#pragma unroll
      for (int j = 0; j < 4; j++) {
        int slot = m0 + rb + j;
        if (MODE == 0 && slot >= Mcur) continue;
#pragma unroll
        for (int nf = 0; nf < NF; nf++) {
          int col = n0 + wn + nf * 16 + (lane & 15);
          float g = acc0[mf][nf][j], u = acc1[mf][nf][j];
          float val = g / (1.f + expf(-g)) * u;
          Hout[(size_t)slot * N + col] = (f16)val;
        }
      }
    }
  } else {
    float* Of = (float*)OutP;
#pragma unroll
    for (int mf = 0; mf < 4; mf++) {
      int rb = wm + mf * 16 + ((lane >> 4) << 2);
#pragma unroll
      for (int j = 0; j < 4; j++) {
        int slot = m0 + rb + j;
        if (MODE == 2) {
          if (slot >= Mcur) continue;
          int tk = tok[slot];
          float w = wtl[slot];
#pragma unroll
          for (int nf = 0; nf < NF; nf++) {
            int col = n0 + wn + nf * 16 + (lane & 15);
            atomicAdd(&Of[(size_t)tk * HDIM + col], acc0[mf][nf][j] * w);
          }
        } else {
#pragma unroll
          for (int nf = 0; nf < NF; nf++) {
            int col = n0 + wn + nf * 16 + (lane & 15);
            Of[(size_t)slot * N + col] = acc0[mf][nf][j];
          }
        }
      }
    }
  }
}

// ---------------- launch ----------------
extern "C" void kernel_launch(void* const* d_in, const int* in_sizes, int n_in,
                              void* d_out, int out_size, void* d_ws, size_t ws_size,
                              hipStream_t stream) {
  const float* x  = (const float*)d_in[0];
  const float* gw = (const float*)d_in[1];
  const float* gb = (const float*)d_in[2];
  const float* w1 = (const float*)d_in[3];
  const float* w2 = (const float*)d_in[4];
  const float* w3 = (const float*)d_in[5];
  const float* sg = (const float*)d_in[6];
  const float* su = (const float*)d_in[7];
  const float* sd = (const float*)d_in[8];
  float* out = (float*)d_out;
  char* ws = (char*)d_ws;

  f16*   xb   = (f16*)(ws);                      // 2048*2048*2  = 8,388,608
  f16*   hs   = (f16*)(ws + 8388608);            // 2048*2048*2  = 8,388,608
  f16*   hbuf = (f16*)(ws + 16777216);           // 32*512*1024*2 = 33,554,432
  int*   tok  = (int*)(ws + 50331648);           // 32*512*4 = 65,536
  float* wt   = (float*)(ws + 50397184);         // 65,536
  int*   tidx = (int*)(ws + 50462720);           // 32,768
  float* tw   = (float*)(ws + 50495488);         // 32,768
  int*   cnt  = (int*)(ws + 50528256);           // 128

  convert_kernel<<<2048, 256, 0, stream>>>(x, xb, 524288);
  gate_kernel<<<2048, 256, 0, stream>>>(x, gw, gb, tidx, tw);
  dispatch_kernel<<<32, 256, 0, stream>>>(tidx, tw, tok, wt, cnt);

  // routed up: per expert, h = silu(Xe@w1)*(Xe@w3)   [K=2048, N=1024]
  gemm_kernel<0, 64><<<dim3(4, 16, 32), 256, 0, stream>>>(
      xb, w1, w3, hbuf, tok, wt, cnt, CAP, 2048, 1024, 2048);
  // shared up: hs = silu(x@sg)*(x@su)                [K=2048, N=2048]
  gemm_kernel<1, 64><<<dim3(16, 32, 1), 256, 0, stream>>>(
      xb, sg, su, hs, nullptr, nullptr, nullptr, 2048, 2048, 2048, 2048);
  // shared down: out = hs @ sd (plain stores)        [K=2048, N=2048]
  gemm_kernel<3, 128><<<dim3(16, 16, 1), 256, 0, stream>>>(
      hs, sd, nullptr, out, nullptr, nullptr, nullptr, 2048, 2048, 2048, 2048);
  // routed down: out += w * (h @ w2) (atomics)       [K=1024, N=2048]
  gemm_kernel<2, 128><<<dim3(4, 16, 32), 256, 0, stream>>>(
      hbuf, w2, nullptr, out, tok, wt, cnt, CAP, 1024, 2048, 1024);
}

// Round 2
// 696.596 us; speedup vs baseline: 1.1041x; 1.1041x over previous
//
#include <hip/hip_runtime.h>
#include <stdint.h>
#include <math.h>

#define NTOK 2048
#define HDIM 2048
#define FDIM 1024
#define NEXP 32
#define TOPK 4
#define NGRP 4
#define CAP  512

typedef _Float16 f16;
typedef _Float16 half8 __attribute__((ext_vector_type(8)));
typedef _Float16 half2v __attribute__((ext_vector_type(2)));
typedef float f32x4 __attribute__((ext_vector_type(4)));

__device__ __forceinline__ int swz(int r) { return (r ^ (r >> 3)) & 7; }

__device__ __forceinline__ void gll16(const void* g, void* l) {
  __builtin_amdgcn_global_load_lds((const __attribute__((address_space(1))) void*)g,
                                   (__attribute__((address_space(3))) void*)l, 16, 0, 0);
}

// ---------------- convert x (fp32) -> xb (fp16) ----------------
__global__ __launch_bounds__(256) void convert_kernel(const float* __restrict__ x,
                                                      f16* __restrict__ xb, int n8) {
  int i = blockIdx.x * 256 + threadIdx.x;
  if (i >= n8) return;
  const f32x4* p = (const f32x4*)(x + (size_t)i * 8);
  f32x4 a = p[0], b = p[1];
  half8 v;
  v[0] = (f16)a[0]; v[1] = (f16)a[1]; v[2] = (f16)a[2]; v[3] = (f16)a[3];
  v[4] = (f16)b[0]; v[5] = (f16)b[1]; v[6] = (f16)b[2]; v[7] = (f16)b[3];
  *(half8*)(xb + (size_t)i * 8) = v;
}

// ---------------- gate ----------------
__global__ __launch_bounds__(256) void gate_kernel(const float* __restrict__ x,
                                                   const float* __restrict__ gw,
                                                   const float* __restrict__ gb,
                                                   int* __restrict__ tidx,
                                                   float* __restrict__ tw) {
  int t = blockIdx.x;
  int tid = threadIdx.x;
  int e = tid >> 3, p = tid & 7;
  const float* xr = x + (size_t)t * HDIM;
  const float* wr = gw + (size_t)e * HDIM;
  float s = 0.f;
  for (int i = p; i < HDIM; i += 8) s += xr[i] * wr[i];
  s += __shfl_down(s, 4, 8);
  s += __shfl_down(s, 2, 8);
  s += __shfl_down(s, 1, 8);
  __shared__ float lg[NEXP];
  if (p == 0) lg[e] = s;
  __syncthreads();
  if (tid == 0) {
    float sc[NEXP], scb[NEXP];
    for (int i = 0; i < NEXP; i++) {
      sc[i] = 1.f / (1.f + expf(-lg[i]));
      scb[i] = sc[i] + gb[i];
    }
    float gs[NGRP];
    for (int g = 0; g < NGRP; g++) {
      float m1 = -1e30f, m2 = -1e30f;
      for (int j = 0; j < 8; j++) {
        float v = scb[g * 8 + j];
        if (v > m1) { m2 = m1; m1 = v; }
        else if (v > m2) m2 = v;
      }
      gs[g] = m1 + m2;
    }
    int g1 = 0; float bv = gs[0];
    for (int g = 1; g < NGRP; g++) if (gs[g] > bv) { bv = gs[g]; g1 = g; }
    int g2 = -1; bv = -1e30f;
    for (int g = 0; g < NGRP; g++) if (g != g1 && gs[g] > bv) { bv = gs[g]; g2 = g; }
    float cand[NEXP];
    for (int i = 0; i < NEXP; i++) {
      int g = i >> 3;
      cand[i] = (g == g1 || g == g2) ? scb[i] : 0.0f;
    }
    int isel[TOPK]; float wsel[TOPK]; float wsum = 0.f;
    bool used[NEXP] = {};
    for (int k = 0; k < TOPK; k++) {
      int best = 0; float bw = -1e30f;
      for (int i = 0; i < NEXP; i++)
        if (!used[i] && cand[i] > bw) { bw = cand[i]; best = i; }
      used[best] = true;
      isel[k] = best;
      wsel[k] = sc[best];
      wsum += wsel[k];
    }
    float inv = 2.0f / (wsum + 1e-20f);
    for (int k = 0; k < TOPK; k++) {
      tidx[t * TOPK + k] = isel[k];
      tw[t * TOPK + k] = wsel[k] * inv;
    }
  }
}

// ---------------- dispatch ----------------
__global__ __launch_bounds__(256) void dispatch_kernel(const int* __restrict__ tidx,
                                                       const float* __restrict__ tw,
                                                       int* __restrict__ tok,
                                                       float* __restrict__ wt,
                                                       int* __restrict__ cnt) {
  int e = blockIdx.x, tid = threadIdx.x, wv = tid >> 6, lane = tid & 63;
  __shared__ int wsum[4];
  __shared__ int sbase;
  if (tid == 0) sbase = 0;
  __syncthreads();
  for (int c = 0; c < (NTOK * TOPK) / 256; c++) {
    int i = c * 256 + tid;
    int fe = tidx[i];
    bool flag = (fe == e);
    unsigned long long b = __ballot(flag ? 1 : 0);
    int lr = __popcll(b & ((1ull << lane) - 1ull));
    if (lane == 0) wsum[wv] = __popcll(b);
    __syncthreads();
    int off = 0;
    for (int w2 = 0; w2 < wv; w2++) off += wsum[w2];
    int tot = wsum[0] + wsum[1] + wsum[2] + wsum[3];
    int base = sbase;
    if (flag) {
      int pos = base + off + lr;
      if (pos < CAP) {
        tok[e * CAP + pos] = i >> 2;
        wt[e * CAP + pos] = tw[i];
      }
    }
    __syncthreads();
    if (tid == 0) sbase = base + tot;
  }
  __syncthreads();
  if (tid == 0) cnt[e] = min(sbase, CAP);
}

// ---------------- pipelined MFMA GEMM ----------------
// MODE 0: routed up (dual w1/w3, gathered A, silu-mul -> h fp16)
// MODE 1: shared up (dual sg/su, linear A, -> hs fp16)
// MODE 2: routed down (w2, A=h[e], atomicAdd out)
// MODE 3: shared down (sd, A=hs, plain store out)
template<int MODE, int BN>
__global__ __launch_bounds__(256, 2) void gemm_kernel(
    const f16* __restrict__ Abase, const float* __restrict__ B0g, const float* __restrict__ B1g,
    void* __restrict__ OutP, const int* __restrict__ tokL, const float* __restrict__ wtL,
    const int* __restrict__ cntP, int K, int N, int ldA) {
  constexpr int BM = 128, BK = 64;
  constexpr bool DUAL = (MODE == 0 || MODE == 1);
  constexpr bool ROUTED = (MODE == 0 || MODE == 2);
  constexpr int NF = BN / 32;
  constexpr int WN = BN / 2;
  constexpr int TPR = BN / 4;      // threads per k-row (float4 granularity)
  constexpr int RPI = 512 / TPR;   // k-rows covered per iter
  constexpr int ITER = BK / RPI;   // iters per matrix per tile

  int e = blockIdx.z;
  int m0 = blockIdx.x * BM, n0 = blockIdx.y * BN;
  int Mcur = 1 << 30;
  const f16* A = Abase;
  const float* B0 = B0g;
  const float* B1 = B1g;
  const int* tok = tokL;
  const float* wtl = wtL;
  if (ROUTED) {
    Mcur = cntP[e];
    if (m0 >= Mcur) return;
    B0 += (size_t)e * K * N;
    if (DUAL) B1 += (size_t)e * K * N;
    tok += e * CAP;
    wtl += e * CAP;
    if (MODE == 2) A += (size_t)e * CAP * (size_t)ldA;
  }

  __shared__ __align__(16) char smem[2 * BM * BK * 2 + (DUAL ? 2 : 1) * BN * BK * 2];
  char* As = smem;                         // 2 x 16KB double buffer
  char* Bs0 = smem + 2 * BM * BK * 2;
  char* Bs1 = Bs0 + BN * BK * 2;

  int tid = threadIdx.x, lane = tid & 63, wv = tid >> 6;
  int wm = (wv >> 1) * 64, wn = (wv & 1) * WN;

  // A source pointers for global_load_lds: linear LDS dest, pre-swizzled global src.
  // LDS slot (r, s) holds global chunk c = s ^ swz(r), so b128 frag reads are conflict-free.
  const f16* asrc[4];
#pragma unroll
  for (int j = 0; j < 4; j++) {
    int r = j * 32 + wv * 8 + (lane >> 3);
    int c = (lane & 7) ^ swz(r);
    int gr = m0 + r;
    const f16* base;
    if (MODE == 0) {
      int rr = gr < Mcur ? gr : (Mcur - 1);
      base = A + (size_t)tok[rr] * ldA;
    } else {
      base = A + (size_t)gr * ldA;
    }
    asrc[j] = base + c * 8;
  }

  f32x4 br0[2 * ITER];
  f32x4 br1[DUAL ? 2 * ITER : 1];

  f32x4 acc0[4][NF];
  f32x4 acc1[4][NF];
#pragma unroll
  for (int mf = 0; mf < 4; mf++)
#pragma unroll
    for (int nf = 0; nf < NF; nf++) {
      acc0[mf][nf] = (f32x4){0.f, 0.f, 0.f, 0.f};
      acc1[mf][nf] = (f32x4){0.f, 0.f, 0.f, 0.f};
    }

  int kp0 = 2 * (tid / TPR);
  int nn0 = 4 * (tid % TPR);

  auto loadA = [&](int t) {
#pragma unroll
    for (int j = 0; j < 4; j++)
      gll16(asrc[j] + (size_t)t * BK, As + (t & 1) * 16384 + j * 4096 + wv * 1024);
  };
  auto loadB = [&](int t) {
    int k0 = t * BK;
#pragma unroll
    for (int i = 0; i < ITER; i++) {
      int kp = kp0 + i * RPI;
      const float* s0 = B0 + (size_t)(k0 + kp) * N + n0 + nn0;
      br0[2 * i] = *(const f32x4*)s0;
      br0[2 * i + 1] = *(const f32x4*)(s0 + N);
      if constexpr (DUAL) {
        const float* s1 = B1 + (size_t)(k0 + kp) * N + n0 + nn0;
        br1[2 * i] = *(const f32x4*)s1;
        br1[2 * i + 1] = *(const f32x4*)(s1 + N);
      }
    }
  };
  auto writeB = [&]() {
#pragma unroll
    for (int i = 0; i < ITER; i++) {
      int kp = kp0 + i * RPI;
#pragma unroll
      for (int q = 0; q < 4; q++) {
        int n = nn0 + q;
        int off = n * 128 + (((kp >> 3) ^ swz(n)) << 4) + (kp & 7) * 2;
        half2v h0;
        h0[0] = (f16)br0[2 * i][q];
        h0[1] = (f16)br0[2 * i + 1][q];
        *(half2v*)(Bs0 + off) = h0;
        if constexpr (DUAL) {
          half2v h1;
          h1[0] = (f16)br1[2 * i][q];
          h1[1] = (f16)br1[2 * i + 1][q];
          *(half2v*)(Bs1 + off) = h1;
        }
      }
    }
  };
  auto compute = [&](int t) {
    char* Ab = As + (t & 1) * 16384;
#pragma unroll
    for (int kk = 0; kk < 2; kk++) {
      half8 af[4];
#pragma unroll
      for (int mf = 0; mf < 4; mf++) {
        int r = wm + mf * 16 + (lane & 15);
        af[mf] = *(const half8*)(Ab + r * 128 + ((((kk << 2) + (lane >> 4)) ^ swz(r)) << 4));
      }
      half8 bf0[NF], bf1[NF];
#pragma unroll
      for (int nf = 0; nf < NF; nf++) {
        int n = wn + nf * 16 + (lane & 15);
        int off = n * 128 + ((((kk << 2) + (lane >> 4)) ^ swz(n)) << 4);
        bf0[nf] = *(const half8*)(Bs0 + off);
        if constexpr (DUAL) bf1[nf] = *(const half8*)(Bs1 + off);
      }
#pragma unroll
      for (int mf = 0; mf < 4; mf++)
#pragma unroll
        for (int nf = 0; nf < NF; nf++) {
          acc0[mf][nf] = __builtin_amdgcn_mfma_f32_16x16x32_f16(af[mf], bf0[nf], acc0[mf][nf], 0, 0, 0);
          if constexpr (DUAL)
            acc1[mf][nf] = __builtin_amdgcn_mfma_f32_16x16x32_f16(af[mf], bf1[nf], acc1[mf][nf], 0, 0, 0);
        }
    }
  };

  int nk = K / BK;
  loadB(0);
  loadA(0);
  writeB();
  __syncthreads();   // drains gll(0) + publishes B tile 0
  for (int t = 0; t < nk; t++) {
    if (t + 1 < nk) {
      loadB(t + 1);   // global -> regs, latency hidden under compute
      loadA(t + 1);   // global -> LDS (other buffer), drained at next barrier
    }
    compute(t);
    __syncthreads();
    if (t + 1 < nk) writeB();
    __syncthreads();
  }

  // epilogue
  if (MODE == 0 || MODE == 1) {
    f16* Hout = (f16*)OutP;
    if (MODE == 0) Hout += (size_t)e * CAP * FDIM;
#pragma unroll
    for (int mf = 0; mf < 4; mf++) {
      int rb = wm + mf * 16 + ((lane >> 4) << 2);
#pragma unroll
      for (int j = 0; j < 4; j++) {
        int slot = m0 + rb + j;
        if (MODE == 0 && slot >= Mcur) continue;
#pragma unroll
        for (int nf = 0; nf < NF; nf++) {
          int col = n0 + wn + nf * 16 + (lane & 15);
          float g = acc0[mf][nf][j], u = acc1[mf][nf][j];
          float val = g / (1.f + expf(-g)) * u;
          Hout[(size_t)slot * N + col] = (f16)val;
        }
      }
    }
  } else {
    float* Of = (float*)OutP;
#pragma unroll
    for (int mf = 0; mf < 4; mf++) {
      int rb = wm + mf * 16 + ((lane >> 4) << 2);
#pragma unroll
      for (int j = 0; j < 4; j++) {
        int slot = m0 + rb + j;
        if (MODE == 2) {
          if (slot >= Mcur) continue;
          int tk = tok[slot];
          float w = wtl[slot];
#pragma unroll
          for (int nf = 0; nf < NF; nf++) {
            int col = n0 + wn + nf * 16 + (lane & 15);
            atomicAdd(&Of[(size_t)tk * HDIM + col], acc0[mf][nf][j] * w);
          }
        } else {
#pragma unroll
          for (int nf = 0; nf < NF; nf++) {
            int col = n0 + wn + nf * 16 + (lane & 15);
            Of[(size_t)slot * N + col] = acc0[mf][nf][j];
          }
        }
      }
    }
  }
}

// ---------------- launch ----------------
extern "C" void kernel_launch(void* const* d_in, const int* in_sizes, int n_in,
                              void* d_out, int out_size, void* d_ws, size_t ws_size,
                              hipStream_t stream) {
  const float* x  = (const float*)d_in[0];
  const float* gw = (const float*)d_in[1];
  const float* gb = (const float*)d_in[2];
  const float* w1 = (const float*)d_in[3];
  const float* w2 = (const float*)d_in[4];
  const float* w3 = (const float*)d_in[5];
  const float* sg = (const float*)d_in[6];
  const float* su = (const float*)d_in[7];
  const float* sd = (const float*)d_in[8];
  float* out = (float*)d_out;
  char* ws = (char*)d_ws;

  f16*   xb   = (f16*)(ws);                      // 8,388,608 B
  f16*   hs   = (f16*)(ws + 8388608);            // 8,388,608 B
  f16*   hbuf = (f16*)(ws + 16777216);           // 33,554,432 B
  int*   tok  = (int*)(ws + 50331648);
  float* wt   = (float*)(ws + 50397184);
  int*   tidx = (int*)(ws + 50462720);
  float* tw   = (float*)(ws + 50495488);
  int*   cnt  = (int*)(ws + 50528256);

  convert_kernel<<<2048, 256, 0, stream>>>(x, xb, 524288);
  gate_kernel<<<2048, 256, 0, stream>>>(x, gw, gb, tidx, tw);
  dispatch_kernel<<<32, 256, 0, stream>>>(tidx, tw, tok, wt, cnt);

  // routed up: h = silu(Xe@w1)*(Xe@w3)   [K=2048, N=1024]
  gemm_kernel<0, 64><<<dim3(4, 16, 32), 256, 0, stream>>>(
      xb, w1, w3, hbuf, tok, wt, cnt, 2048, 1024, 2048);
  // shared up: hs = silu(x@sg)*(x@su)    [K=2048, N=2048]
  gemm_kernel<1, 64><<<dim3(16, 32, 1), 256, 0, stream>>>(
      xb, sg, su, hs, nullptr, nullptr, nullptr, 2048, 2048, 2048);
  // shared down: out = hs @ sd           [K=2048, N=2048]
  gemm_kernel<3, 128><<<dim3(16, 16, 1), 256, 0, stream>>>(
      hs, sd, nullptr, out, nullptr, nullptr, nullptr, 2048, 2048, 2048);
  // routed down: out += w * (h @ w2)     [K=1024, N=2048]
  gemm_kernel<2, 128><<<dim3(4, 16, 32), 256, 0, stream>>>(
      hbuf, w2, nullptr, out, tok, wt, cnt, 1024, 2048, 1024);
}